// Round 1
// 1107.876 us; speedup vs baseline: 1.0020x; 1.0020x over previous
//
#include <hip/hip_runtime.h>

// GRU, 25 steps, UNITS=16, fed-back output (inp == h for steps >= 2).
// 16 lanes per row-group; lane owns unit u; each lane now carries J=4 rows
// for in-wave ILP (the per-step sigmoid/tanh + LDS-roundtrip latency of one
// row hides under the FMA streams of the other three). Weights stay
// register-resident (combined K+RK columns for z/r). h replicated across
// the 16-lane group via 1 ds_write + 4 broadcast ds_read_b128 per row;
// groups never span waves -> no __syncthreads anywhere.
// LDS group stride padded to 68 floats so the 4 groups of a wave hit
// disjoint banks on the broadcast reads.

#define UNITS 16
#define STEPS 25
#define J 4                         // rows per thread
#define GROUPS 16                   // 16-lane groups per 256-thread block
#define ROWS_PER_BLOCK (GROUPS * J) // 64
#define BLOCK_THREADS 256
#define GSTRIDE (J * UNITS + 4)     // 68 floats: bank-spread across wave's 4 groups

__device__ __forceinline__ float fast_rcp(float x)  { return __builtin_amdgcn_rcpf(x); }
__device__ __forceinline__ float fast_exp2(float x) { return __builtin_amdgcn_exp2f(x); }

__device__ __forceinline__ float fast_sigmoid(float x) {
    // 1 / (1 + exp(-x)) ; exp(-x) = 2^(-x*log2e). Saturates correctly via inf.
    return fast_rcp(1.0f + fast_exp2(x * -1.4426950408889634f));
}
__device__ __forceinline__ float fast_tanh(float x) {
    // 1 - 2/(1 + exp(2x))
    return 1.0f - 2.0f * fast_rcp(1.0f + fast_exp2(x * 2.8853900817779268f));
}

__global__ __launch_bounds__(BLOCK_THREADS, 2)
void gru_seq_kernel(const float* __restrict__ x,
                    const float* __restrict__ K,    // [16][48] z|r|h
                    const float* __restrict__ RK,   // [16][48]
                    const float* __restrict__ bias, // [2][48]  b_i | b_r
                    float* __restrict__ out,        // [B][25][16]
                    int B)
{
    __shared__ float lds_h[GROUPS * GSTRIDE];

    const int tid = threadIdx.x;
    const int u   = tid & (UNITS - 1);
    const int g   = tid >> 4;
    const int row0 = blockIdx.x * ROWS_PER_BLOCK + g * J;

    float* lds_grp = &lds_h[g * GSTRIDE];

    // biases for own unit column
    const float bi_z = bias[u],          br_z = bias[48 + u];
    const float bi_r = bias[16 + u],     br_r = bias[48 + 16 + u];
    const float bi_h = bias[32 + u],     br_h = bias[48 + 32 + u];

    bool  act[J];
    float h_my[J];
    #pragma unroll
    for (int j = 0; j < J; ++j) {
        const int r = row0 + j;
        act[j]  = r < B;
        h_my[j] = act[j] ? x[(size_t)r * UNITS + u] : 0.0f;
    }

    float* op[J];
    #pragma unroll
    for (int j = 0; j < J; ++j)
        op[j] = out + (size_t)(row0 + j) * (STEPS * UNITS) + u;

    float hrep[J][16];

    // replicate x across the 16-lane group (same wave -> ordered LDS, no barrier)
    #pragma unroll
    for (int j = 0; j < J; ++j) lds_grp[j * UNITS + u] = h_my[j];
    #pragma unroll
    for (int j = 0; j < J; ++j) {
        const float4* p = (const float4*)&lds_grp[j * UNITS];
        float4 a = p[0], b = p[1], c = p[2], d = p[3];
        hrep[j][0]=a.x;  hrep[j][1]=a.y;  hrep[j][2]=a.z;  hrep[j][3]=a.w;
        hrep[j][4]=b.x;  hrep[j][5]=b.y;  hrep[j][6]=b.z;  hrep[j][7]=b.w;
        hrep[j][8]=c.x;  hrep[j][9]=c.y;  hrep[j][10]=c.z; hrep[j][11]=c.w;
        hrep[j][12]=d.x; hrep[j][13]=d.y; hrep[j][14]=d.z; hrep[j][15]=d.w;
    }

    // ---- step 0: inp = 0 (x_proj = b_i), h = x ----
    #pragma unroll
    for (int j = 0; j < J; ++j) {
        float az = bi_z + br_z;
        float ar = bi_r + br_r;
        float ah = br_h;
        #pragma unroll
        for (int k = 0; k < 16; ++k) {
            float xk = hrep[j][k];
            az = fmaf(xk, RK[k*48 + u],      az);
            ar = fmaf(xk, RK[k*48 + 16 + u], ar);
            ah = fmaf(xk, RK[k*48 + 32 + u], ah);
        }
        float z  = fast_sigmoid(az);
        float r  = fast_sigmoid(ar);
        float hh = fast_tanh(fmaf(r, ah, bi_h));
        float hn = fmaf(z, h_my[j] - hh, hh);   // z*h + (1-z)*hh
        if (act[j]) op[j][0] = hn;
        h_my[j] = hn;
    }

    // register-resident combined weight columns for steps >= 1 (inp == h)
    float Wz[16], Wr[16], Wh[16], Uh[16];
    #pragma unroll
    for (int k = 0; k < 16; ++k) {
        Wz[k] = K[k*48 + u]      + RK[k*48 + u];
        Wr[k] = K[k*48 + 16 + u] + RK[k*48 + 16 + u];
        Wh[k] = K[k*48 + 32 + u];
        Uh[k] = RK[k*48 + 32 + u];
    }
    const float bz  = bi_z + br_z;
    const float brr = bi_r + br_r;

    #pragma unroll 1
    for (int t = 1; t < STEPS; ++t) {
        // re-replicate h (write own, read group's 16) — same wave, in order
        #pragma unroll
        for (int j = 0; j < J; ++j) lds_grp[j * UNITS + u] = h_my[j];
        #pragma unroll
        for (int j = 0; j < J; ++j) {
            const float4* p = (const float4*)&lds_grp[j * UNITS];
            float4 a = p[0], b = p[1], c = p[2], d = p[3];
            hrep[j][0]=a.x;  hrep[j][1]=a.y;  hrep[j][2]=a.z;  hrep[j][3]=a.w;
            hrep[j][4]=b.x;  hrep[j][5]=b.y;  hrep[j][6]=b.z;  hrep[j][7]=b.w;
            hrep[j][8]=c.x;  hrep[j][9]=c.y;  hrep[j][10]=c.z; hrep[j][11]=c.w;
            hrep[j][12]=d.x; hrep[j][13]=d.y; hrep[j][14]=d.z; hrep[j][15]=d.w;
        }

        float az[J], ar[J], axh[J], arh[J];
        #pragma unroll
        for (int j = 0; j < J; ++j) { az[j]=bz; ar[j]=brr; axh[j]=bi_h; arh[j]=br_h; }

        // 16 independent accumulator chains (4 rows x 4 gates) — issue-dense
        #pragma unroll
        for (int k = 0; k < 16; ++k) {
            #pragma unroll
            for (int j = 0; j < J; ++j) {
                float hk = hrep[j][k];
                az[j]  = fmaf(hk, Wz[k], az[j]);
                ar[j]  = fmaf(hk, Wr[k], ar[j]);
                axh[j] = fmaf(hk, Wh[k], axh[j]);
                arh[j] = fmaf(hk, Uh[k], arh[j]);
            }
        }

        #pragma unroll
        for (int j = 0; j < J; ++j) {
            float z  = fast_sigmoid(az[j]);
            float r  = fast_sigmoid(ar[j]);
            float hh = fast_tanh(fmaf(r, arh[j], axh[j]));
            float hn = fmaf(z, h_my[j] - hh, hh);
            if (act[j]) op[j][t * UNITS] = hn;
            h_my[j] = hn;
        }
    }
}

extern "C" void kernel_launch(void* const* d_in, const int* in_sizes, int n_in,
                              void* d_out, int out_size, void* d_ws, size_t ws_size,
                              hipStream_t stream) {
    const float* x    = (const float*)d_in[0];
    const float* K    = (const float*)d_in[1];
    const float* RK   = (const float*)d_in[2];
    const float* bias = (const float*)d_in[3];
    float* out = (float*)d_out;

    const int B = in_sizes[0] / UNITS;
    const int grid = (B + ROWS_PER_BLOCK - 1) / ROWS_PER_BLOCK;
    gru_seq_kernel<<<grid, BLOCK_THREADS, 0, stream>>>(x, K, RK, bias, out, B);
}

// Round 2
// 1075.565 us; speedup vs baseline: 1.0321x; 1.0300x over previous
//
#include <hip/hip_runtime.h>

// GRU, 25 steps, UNITS=16, fed-back output (inp == h for steps >= 2).
// 16 lanes per row; lane owns unit u. Weights register-resident per lane
// (combined K+RK columns for z/r). h replicated across the 16-lane group
// via 1 ds_write + 4 broadcast ds_read_b128 per step; groups never span
// waves -> no per-step barrier.
//
// Round-2 change: per-step global stores (4B/lane -> 64B chunks at 1600B
// stride, temporally scattered across the whole kernel; theory: partially
// dirty L2 lines evicted as 64B fragments pin HBM write efficiency at
// ~1.5 TB/s) are replaced by LDS out-staging ([16 rows][25 t][16 u] =
// 25.6 KB) + one fully-coalesced float4 burst copy of the block's
// contiguous 25.6 KB output region at kernel end.

#define UNITS 16
#define STEPS 25
#define ROWS_PER_BLOCK 16
#define BLOCK_THREADS 256
#define ROW_FLOATS (STEPS * UNITS)                  // 400 floats per row
#define OUT_FLOATS (ROWS_PER_BLOCK * ROW_FLOATS)    // 6400 floats = 25.6 KB
#define OUT_F4     (OUT_FLOATS / 4)                 // 1600 float4 per block

__device__ __forceinline__ float fast_rcp(float x)  { return __builtin_amdgcn_rcpf(x); }
__device__ __forceinline__ float fast_exp2(float x) { return __builtin_amdgcn_exp2f(x); }

__device__ __forceinline__ float fast_sigmoid(float x) {
    // 1 / (1 + exp(-x)) ; exp(-x) = 2^(-x*log2e). Saturates correctly via inf.
    return fast_rcp(1.0f + fast_exp2(x * -1.4426950408889634f));
}
__device__ __forceinline__ float fast_tanh(float x) {
    // 1 - 2/(1 + exp(2x))
    return 1.0f - 2.0f * fast_rcp(1.0f + fast_exp2(x * 2.8853900817779268f));
}

__global__ __launch_bounds__(BLOCK_THREADS, 4)
void gru_seq_kernel(const float* __restrict__ x,
                    const float* __restrict__ K,    // [16][48] z|r|h
                    const float* __restrict__ RK,   // [16][48]
                    const float* __restrict__ bias, // [2][48]  b_i | b_r
                    float* __restrict__ out,        // [B][25][16]
                    int B)
{
    __shared__ float lds_h[ROWS_PER_BLOCK * UNITS]; // 1 KiB h-replication
    __shared__ float lds_out[OUT_FLOATS];           // 25.6 KiB out staging

    const int tid = threadIdx.x;
    const int u   = tid & (UNITS - 1);
    const int g   = tid >> 4;
    const int row = blockIdx.x * ROWS_PER_BLOCK + g;
    const bool active = row < B;

    float* lds_grp = &lds_h[g * UNITS];
    // own output column inside the staging buffer: [g][t][u], stride 16 floats over t
    float* lds_og  = &lds_out[g * ROW_FLOATS + u];

    // biases for own unit column
    const float bi_z = bias[u],          br_z = bias[48 + u];
    const float bi_r = bias[16 + u],     br_r = bias[48 + 16 + u];
    const float bi_h = bias[32 + u],     br_h = bias[48 + 32 + u];

    float h_my = active ? x[(size_t)row * UNITS + u] : 0.0f;

    float hrep[16];
    // replicate x across the 16-lane group (same wave -> ordered LDS, no barrier)
    {
        lds_grp[u] = h_my;
        const float4* p = (const float4*)lds_grp;
        float4 a = p[0], b = p[1], c = p[2], d = p[3];
        hrep[0]=a.x;  hrep[1]=a.y;  hrep[2]=a.z;  hrep[3]=a.w;
        hrep[4]=b.x;  hrep[5]=b.y;  hrep[6]=b.z;  hrep[7]=b.w;
        hrep[8]=c.x;  hrep[9]=c.y;  hrep[10]=c.z; hrep[11]=c.w;
        hrep[12]=d.x; hrep[13]=d.y; hrep[14]=d.z; hrep[15]=d.w;
    }

    // ---- step 0: inp = 0 (x_proj = b_i), h = x ----
    {
        float az = bi_z + br_z;
        float ar = bi_r + br_r;
        float ah = br_h;
        #pragma unroll
        for (int k = 0; k < 16; ++k) {
            float xk = hrep[k];
            az = fmaf(xk, RK[k*48 + u],      az);
            ar = fmaf(xk, RK[k*48 + 16 + u], ar);
            ah = fmaf(xk, RK[k*48 + 32 + u], ah);
        }
        float z  = fast_sigmoid(az);
        float r  = fast_sigmoid(ar);
        float hh = fast_tanh(fmaf(r, ah, bi_h));
        float hn = fmaf(z, h_my - hh, hh);   // z*h + (1-z)*hh
        lds_og[0] = hn;                      // LDS staging, no global store
        h_my = hn;
    }

    // register-resident combined weight columns for steps >= 1 (inp == h)
    float Wz[16], Wr[16], Wh[16], Uh[16];
    #pragma unroll
    for (int k = 0; k < 16; ++k) {
        Wz[k] = K[k*48 + u]      + RK[k*48 + u];
        Wr[k] = K[k*48 + 16 + u] + RK[k*48 + 16 + u];
        Wh[k] = K[k*48 + 32 + u];
        Uh[k] = RK[k*48 + 32 + u];
    }
    const float bz  = bi_z + br_z;
    const float brr = bi_r + br_r;

    #pragma unroll 1
    for (int t = 1; t < STEPS; ++t) {
        // re-replicate h (write own, read group's 16) — same wave, in order
        lds_grp[u] = h_my;
        const float4* p = (const float4*)lds_grp;
        float4 a = p[0], b = p[1], c = p[2], d = p[3];
        hrep[0]=a.x;  hrep[1]=a.y;  hrep[2]=a.z;  hrep[3]=a.w;
        hrep[4]=b.x;  hrep[5]=b.y;  hrep[6]=b.z;  hrep[7]=b.w;
        hrep[8]=c.x;  hrep[9]=c.y;  hrep[10]=c.z; hrep[11]=c.w;
        hrep[12]=d.x; hrep[13]=d.y; hrep[14]=d.z; hrep[15]=d.w;

        float az = bz, ar = brr, axh = bi_h, arh = br_h;
        #pragma unroll
        for (int k = 0; k < 16; ++k) {
            float hk = hrep[k];
            az  = fmaf(hk, Wz[k], az);
            ar  = fmaf(hk, Wr[k], ar);
            axh = fmaf(hk, Wh[k], axh);
            arh = fmaf(hk, Uh[k], arh);
        }
        float z  = fast_sigmoid(az);
        float r  = fast_sigmoid(ar);
        float hh = fast_tanh(fmaf(r, arh, axh));
        float hn = fmaf(z, h_my - hh, hh);
        lds_og[t * UNITS] = hn;              // LDS staging (bank-alias 2-way = free)
        h_my = hn;
    }

    // ---- coalesced burst write of the block's contiguous 25.6 KB region ----
    __syncthreads();

    const float4* lsrc = (const float4*)lds_out;
    float4* gdst = (float4*)(out + (size_t)blockIdx.x * OUT_FLOATS);
    const int row0 = blockIdx.x * ROWS_PER_BLOCK;

    if (row0 + ROWS_PER_BLOCK <= B) {
        // full block: straight streaming copy, 4 KB per block-iteration
        #pragma unroll 1
        for (int i = tid; i < OUT_F4; i += BLOCK_THREADS)
            gdst[i] = lsrc[i];
    } else {
        // partial tail block: guard per row
        #pragma unroll 1
        for (int i = tid; i < OUT_F4; i += BLOCK_THREADS) {
            int r = i / (ROW_FLOATS / 4);   // 100 float4 per row
            if (row0 + r < B) gdst[i] = lsrc[i];
        }
    }
}

extern "C" void kernel_launch(void* const* d_in, const int* in_sizes, int n_in,
                              void* d_out, int out_size, void* d_ws, size_t ws_size,
                              hipStream_t stream) {
    const float* x    = (const float*)d_in[0];
    const float* K    = (const float*)d_in[1];
    const float* RK   = (const float*)d_in[2];
    const float* bias = (const float*)d_in[3];
    float* out = (float*)d_out;

    const int B = in_sizes[0] / UNITS;
    const int grid = (B + ROWS_PER_BLOCK - 1) / ROWS_PER_BLOCK;
    gru_seq_kernel<<<grid, BLOCK_THREADS, 0, stream>>>(x, K, RK, bias, out, B);
}